// Round 5
// baseline (2556.069 us; speedup 1.0000x reference)
//
#include <hip/hip_runtime.h>

#define N_NODES 100000
#define N_EDGES 1600000
#define HID 128
#define NUM_LAYERS 10
#define NUM_GRAPHS 64
#define SCAN_BLOCKS ((N_NODES + 255) / 256)
#define IDX_CAP 2048   // LDS-staged neighbor indices per 64-node block (mean 1024, sigma ~32)

// ---------------- CSR build ----------------

__global__ __launch_bounds__(256) void count_deg_kernel(const int* __restrict__ dst,
                                                        int* __restrict__ deg, int E) {
  int e = blockIdx.x * 256 + threadIdx.x;
  if (e < E) atomicAdd(&deg[dst[e]], 1);
}

__global__ __launch_bounds__(256) void block_sum_kernel(const int* __restrict__ deg,
                                                        int* __restrict__ psum, int n) {
  __shared__ int sd[256];
  int i = blockIdx.x * 256 + threadIdx.x;
  sd[threadIdx.x] = (i < n) ? deg[i] : 0;
  __syncthreads();
  for (int off = 128; off > 0; off >>= 1) {
    if (threadIdx.x < off) sd[threadIdx.x] += sd[threadIdx.x + off];
    __syncthreads();
  }
  if (threadIdx.x == 0) psum[blockIdx.x] = sd[0];
}

__global__ __launch_bounds__(512) void scan_partials_kernel(const int* __restrict__ psum,
                                                            int* __restrict__ poff, int nb) {
  __shared__ int sd[512];
  int i = threadIdx.x;
  int v = (i < nb) ? psum[i] : 0;
  sd[i] = v;
  __syncthreads();
  for (int off = 1; off < 512; off <<= 1) {
    int t = (i >= off) ? sd[i - off] : 0;
    __syncthreads();
    sd[i] += t;
    __syncthreads();
  }
  if (i < nb) poff[i] = sd[i] - v;  // exclusive
}

__global__ __launch_bounds__(256) void write_rs_kernel(const int* __restrict__ deg,
                                                       const int* __restrict__ poff,
                                                       int* __restrict__ rs,
                                                       int* __restrict__ cur, int n) {
  __shared__ int sd[256];
  int i = blockIdx.x * 256 + threadIdx.x;
  int v = (i < n) ? deg[i] : 0;
  sd[threadIdx.x] = v;
  __syncthreads();
  for (int off = 1; off < 256; off <<= 1) {
    int t = (threadIdx.x >= off) ? sd[threadIdx.x - off] : 0;
    __syncthreads();
    sd[threadIdx.x] += t;
    __syncthreads();
  }
  if (i < n) {
    int incl = poff[blockIdx.x] + sd[threadIdx.x];
    rs[i + 1] = incl;
    cur[i] = incl - v;
  }
  if (i == 0) rs[0] = 0;
}

__global__ __launch_bounds__(256) void fill_csr_kernel(const int* __restrict__ src,
                                                       const int* __restrict__ dst,
                                                       int* __restrict__ cur,
                                                       int* __restrict__ csr, int E) {
  int e = blockIdx.x * 256 + threadIdx.x;
  if (e < E) {
    int p = atomicAdd(&cur[dst[e]], 1);
    csr[p] = src[e];
  }
}

// ---------------- fused layer: gather + MLP ----------------
// xout = relu( relu(h@W1+b1)@W2 + b2 [+h] ) + xin,  h = (1+eps)*xin + sum_{u->v} xin[u]
// 64 rows per 256-thread block. Worker (32 lanes) owns 8 consecutive nodes; its CSR
// edge range is contiguous. Indices + row-starts staged in LDS; edges stream through a
// persistent 8-deep register pipeline crossing node boundaries (flush = owner-exclusive
// LDS read-modify-write). No vm-queue drains between nodes.

__global__ __launch_bounds__(256, 3) void layer_kernel(const float* __restrict__ xin,
                                                       float* __restrict__ xout,
                                                       const int* __restrict__ rs,
                                                       const int* __restrict__ csr,
                                                       const float* __restrict__ eps, int layer,
                                                       const float* __restrict__ W1,
                                                       const float* __restrict__ b1,
                                                       const float* __restrict__ W2,
                                                       const float* __restrict__ b2,
                                                       int n, int addH) {
  __shared__ float lh[64 * 128];
  __shared__ int lidx[IDX_CAP];
  __shared__ int lrs[65];
  const int tid = threadIdx.x;
  const int row0 = blockIdx.x * 64;
  const float4* x4 = (const float4*)xin;
  float4* lh4 = (float4*)lh;
  const float s = 1.0f + eps[layer];

  // ---- Phase 0: stage row starts (local offsets) and CSR indices into LDS.
  int rowEnd = row0 + 64; if (rowEnd > n) rowEnd = n;
  const int eBase = rs[row0];
  const int cnt = rs[rowEnd] - eBase;
  if (tid < 65) {
    int node = row0 + tid; if (node > n) node = n;
    lrs[tid] = rs[node] - eBase;
  }
  const int stage = (cnt < IDX_CAP) ? cnt : IDX_CAP;
  for (int t = tid; t < stage; t += 256) lidx[t] = csr[eBase + t];
  __syncthreads();

  const int w = tid >> 5;
  const int lane = tid & 31;
  const int base8 = 8 * w;

  // ---- Phase 1a: self-init lh rows (owner worker, pipelined loads).
  {
    float4 sv[8];
#pragma unroll
    for (int r = 0; r < 8; ++r) {
      int node = row0 + base8 + r;
      if (node < n) sv[r] = x4[node * 32 + lane];
    }
#pragma unroll
    for (int r = 0; r < 8; ++r) {
      int node = row0 + base8 + r;
      float4 o; o.x = o.y = o.z = o.w = 0.f;
      if (node < n) { o.x = sv[r].x * s; o.y = sv[r].y * s; o.z = sv[r].z * s; o.w = sv[r].w * s; }
      lh4[(base8 + r) * 32 + lane] = o;
    }
  }

  // ---- Phase 1b: stream this worker's edges (contiguous CSR range).
  if (cnt <= IDX_CAP) {
    int eLo = lrs[base8];
    int eHi = lrs[base8 + 8];
    int cn = base8;
    int ce = lrs[base8 + 1];
    int c = eLo;
    float4 acc; acc.x = acc.y = acc.z = acc.w = 0.f;

#define FLUSH_WHILE()                                                      \
    while (c >= ce) {                                                      \
      float4 _t = lh4[cn * 32 + lane];                                     \
      _t.x += acc.x; _t.y += acc.y; _t.z += acc.z; _t.w += acc.w;          \
      lh4[cn * 32 + lane] = _t;                                            \
      acc.x = acc.y = acc.z = acc.w = 0.f;                                 \
      ++cn; ce = lrs[cn + 1];                                              \
    }
#define CONS(B)                                                            \
    { FLUSH_WHILE();                                                       \
      acc.x += (B).x; acc.y += (B).y; acc.z += (B).z; acc.w += (B).w;      \
      ++c; }

    const int np = eHi - eLo;
    if (np >= 8) {
      float4 b0 = x4[lidx[eLo + 0] * 32 + lane];
      float4 b1v = x4[lidx[eLo + 1] * 32 + lane];
      float4 b2v = x4[lidx[eLo + 2] * 32 + lane];
      float4 b3 = x4[lidx[eLo + 3] * 32 + lane];
      float4 b4 = x4[lidx[eLo + 4] * 32 + lane];
      float4 b5 = x4[lidx[eLo + 5] * 32 + lane];
      float4 b6 = x4[lidx[eLo + 6] * 32 + lane];
      float4 b7 = x4[lidx[eLo + 7] * 32 + lane];
      int issue = eLo + 8;
      while (issue + 8 <= eHi) {
        CONS(b0); b0 = x4[lidx[issue + 0] * 32 + lane];
        CONS(b1v); b1v = x4[lidx[issue + 1] * 32 + lane];
        CONS(b2v); b2v = x4[lidx[issue + 2] * 32 + lane];
        CONS(b3); b3 = x4[lidx[issue + 3] * 32 + lane];
        CONS(b4); b4 = x4[lidx[issue + 4] * 32 + lane];
        CONS(b5); b5 = x4[lidx[issue + 5] * 32 + lane];
        CONS(b6); b6 = x4[lidx[issue + 6] * 32 + lane];
        CONS(b7); b7 = x4[lidx[issue + 7] * 32 + lane];
        issue += 8;
      }
      const int rem = eHi - issue;  // 0..7
      float4 r0, r1, r2, r3, r4, r5, r6;
      if (rem > 0) r0 = x4[lidx[issue + 0] * 32 + lane];
      if (rem > 1) r1 = x4[lidx[issue + 1] * 32 + lane];
      if (rem > 2) r2 = x4[lidx[issue + 2] * 32 + lane];
      if (rem > 3) r3 = x4[lidx[issue + 3] * 32 + lane];
      if (rem > 4) r4 = x4[lidx[issue + 4] * 32 + lane];
      if (rem > 5) r5 = x4[lidx[issue + 5] * 32 + lane];
      if (rem > 6) r6 = x4[lidx[issue + 6] * 32 + lane];
      CONS(b0); CONS(b1v); CONS(b2v); CONS(b3);
      CONS(b4); CONS(b5); CONS(b6); CONS(b7);
      if (rem > 0) CONS(r0);
      if (rem > 1) CONS(r1);
      if (rem > 2) CONS(r2);
      if (rem > 3) CONS(r3);
      if (rem > 4) CONS(r4);
      if (rem > 5) CONS(r5);
      if (rem > 6) CONS(r6);
    } else if (np > 0) {
      float4 r0, r1, r2, r3, r4, r5, r6;
      if (np > 0) r0 = x4[lidx[eLo + 0] * 32 + lane];
      if (np > 1) r1 = x4[lidx[eLo + 1] * 32 + lane];
      if (np > 2) r2 = x4[lidx[eLo + 2] * 32 + lane];
      if (np > 3) r3 = x4[lidx[eLo + 3] * 32 + lane];
      if (np > 4) r4 = x4[lidx[eLo + 4] * 32 + lane];
      if (np > 5) r5 = x4[lidx[eLo + 5] * 32 + lane];
      if (np > 6) r6 = x4[lidx[eLo + 6] * 32 + lane];
      if (np > 0) CONS(r0);
      if (np > 1) CONS(r1);
      if (np > 2) CONS(r2);
      if (np > 3) CONS(r3);
      if (np > 4) CONS(r4);
      if (np > 5) CONS(r5);
      if (np > 6) CONS(r6);
    }
    // final flush of the node currently being accumulated
    {
      float4 t = lh4[cn * 32 + lane];
      t.x += acc.x; t.y += acc.y; t.z += acc.z; t.w += acc.w;
      lh4[cn * 32 + lane] = t;
    }
#undef CONS
#undef FLUSH_WHILE
  } else {
    // fallback (block edge count exceeds LDS staging; effectively never taken here)
#pragma unroll
    for (int r = 0; r < 8; ++r) {
      int node = row0 + base8 + r;
      if (node >= n) continue;
      float4 t = lh4[(base8 + r) * 32 + lane];
      int e0 = rs[node], e1 = rs[node + 1];
      for (int e = e0; e < e1; ++e) {
        int u = csr[e];
        float4 v = x4[u * 32 + lane];
        t.x += v.x; t.y += v.y; t.z += v.z; t.w += v.w;
      }
      lh4[(base8 + r) * 32 + lane] = t;
    }
  }
  __syncthreads();

  // ---- Phase 2: GEMM1 (mid = relu(h@W1+b1))
  const int cg = tid & 31;
  const int rg = tid >> 5;
  float acc[8][4];
#pragma unroll
  for (int r = 0; r < 8; ++r) { acc[r][0] = acc[r][1] = acc[r][2] = acc[r][3] = 0.f; }

  for (int k4 = 0; k4 < 32; ++k4) {
    float4 w0 = *(const float4*)(W1 + (k4 * 4 + 0) * 128 + cg * 4);
    float4 w1 = *(const float4*)(W1 + (k4 * 4 + 1) * 128 + cg * 4);
    float4 w2 = *(const float4*)(W1 + (k4 * 4 + 2) * 128 + cg * 4);
    float4 w3 = *(const float4*)(W1 + (k4 * 4 + 3) * 128 + cg * 4);
#pragma unroll
    for (int r = 0; r < 8; ++r) {
      float4 a = *(const float4*)(lh + (rg * 8 + r) * 128 + k4 * 4);
      acc[r][0] += a.x * w0.x + a.y * w1.x + a.z * w2.x + a.w * w3.x;
      acc[r][1] += a.x * w0.y + a.y * w1.y + a.z * w2.y + a.w * w3.y;
      acc[r][2] += a.x * w0.z + a.y * w1.z + a.z * w2.z + a.w * w3.z;
      acc[r][3] += a.x * w0.w + a.y * w1.w + a.z * w2.w + a.w * w3.w;
    }
  }

  // snapshot h values needed in epilogue (before lh is overwritten by mid)
  float4 hreg[8];
#pragma unroll
  for (int r = 0; r < 8; ++r) hreg[r] = *(const float4*)(lh + (rg * 8 + r) * 128 + cg * 4);
  __syncthreads();

  {
    float4 bb = *(const float4*)(b1 + cg * 4);
#pragma unroll
    for (int r = 0; r < 8; ++r) {
      float4 o;
      o.x = fmaxf(acc[r][0] + bb.x, 0.f);
      o.y = fmaxf(acc[r][1] + bb.y, 0.f);
      o.z = fmaxf(acc[r][2] + bb.z, 0.f);
      o.w = fmaxf(acc[r][3] + bb.w, 0.f);
      *(float4*)(lh + (rg * 8 + r) * 128 + cg * 4) = o;
      acc[r][0] = acc[r][1] = acc[r][2] = acc[r][3] = 0.f;
    }
  }
  __syncthreads();

  // ---- Phase 3: GEMM2 (out = mid@W2 + b2)
  for (int k4 = 0; k4 < 32; ++k4) {
    float4 w0 = *(const float4*)(W2 + (k4 * 4 + 0) * 128 + cg * 4);
    float4 w1 = *(const float4*)(W2 + (k4 * 4 + 1) * 128 + cg * 4);
    float4 w2 = *(const float4*)(W2 + (k4 * 4 + 2) * 128 + cg * 4);
    float4 w3 = *(const float4*)(W2 + (k4 * 4 + 3) * 128 + cg * 4);
#pragma unroll
    for (int r = 0; r < 8; ++r) {
      float4 a = *(const float4*)(lh + (rg * 8 + r) * 128 + k4 * 4);
      acc[r][0] += a.x * w0.x + a.y * w1.x + a.z * w2.x + a.w * w3.x;
      acc[r][1] += a.x * w0.y + a.y * w1.y + a.z * w2.y + a.w * w3.y;
      acc[r][2] += a.x * w0.z + a.y * w1.z + a.z * w2.z + a.w * w3.z;
      acc[r][3] += a.x * w0.w + a.y * w1.w + a.z * w2.w + a.w * w3.w;
    }
  }

  // ---- Epilogue: +b2 (+h) -> relu -> +xin, write xout
  float4 b2v = *(const float4*)(b2 + cg * 4);
  float4* xo4 = (float4*)xout;
#pragma unroll
  for (int r = 0; r < 8; ++r) {
    int row = row0 + rg * 8 + r;
    if (row < n) {
      float ox = acc[r][0] + b2v.x;
      float oy = acc[r][1] + b2v.y;
      float oz = acc[r][2] + b2v.z;
      float ow = acc[r][3] + b2v.w;
      if (addH) {
        ox += hreg[r].x; oy += hreg[r].y; oz += hreg[r].z; ow += hreg[r].w;
      }
      ox = fmaxf(ox, 0.f); oy = fmaxf(oy, 0.f); oz = fmaxf(oz, 0.f); ow = fmaxf(ow, 0.f);
      float4 xv = x4[row * 32 + cg];
      float4 o;
      o.x = ox + xv.x; o.y = oy + xv.y; o.z = oz + xv.z; o.w = ow + xv.w;
      xo4[row * 32 + cg] = o;
    }
  }
}

// ---------------- pooling (batch is sorted) ----------------

__global__ __launch_bounds__(128) void pool_kernel(const float* __restrict__ x,
                                                   const int* __restrict__ batch,
                                                   float* __restrict__ pool,
                                                   int* __restrict__ gcnt, int n) {
  const int CH = 512;
  int c = threadIdx.x;
  int n0 = blockIdx.x * CH;
  if (n0 >= n) return;
  int n1 = n0 + CH; if (n1 > n) n1 = n;
  float acc = 0.f;
  int g = batch[n0];
  int cl = 0;
  for (int i = n0; i < n1; ++i) {
    int gi = batch[i];
    if (gi != g) {
      atomicAdd(&pool[g * 128 + c], acc);
      if (c == 0) atomicAdd(&gcnt[g], cl);
      acc = 0.f; cl = 0; g = gi;
    }
    acc += x[i * 128 + c];
    cl++;
  }
  atomicAdd(&pool[g * 128 + c], acc);
  if (c == 0) atomicAdd(&gcnt[g], cl);
}

// ---------------- classifier: one block per graph ----------------

__global__ __launch_bounds__(128) void classifier_kernel(const float* __restrict__ pool,
                                                         const int* __restrict__ gcnt,
                                                         const float* __restrict__ Wc1,
                                                         const float* __restrict__ bc1,
                                                         const float* __restrict__ Wc2,
                                                         const float* __restrict__ bc2,
                                                         float* __restrict__ out) {
  __shared__ float prow[128];
  __shared__ float hid[128];
  int g = blockIdx.x;
  int c = threadIdx.x;
  float cf = (float)gcnt[g];
  if (cf < 1.f) cf = 1.f;
  prow[c] = pool[g * 128 + c] / cf;
  __syncthreads();
  float a = bc1[c];
  for (int k = 0; k < 128; ++k) a += prow[k] * Wc1[k * 128 + c];
  hid[c] = fmaxf(a, 0.f);
  __syncthreads();
  if (c < 2) {
    float a2 = bc2[c];
    for (int k = 0; k < 128; ++k) a2 += hid[k] * Wc2[k * 2 + c];
    out[g * 2 + c] = a2;
  }
}

// ---------------- launch ----------------

extern "C" void kernel_launch(void* const* d_in, const int* in_sizes, int n_in,
                              void* d_out, int out_size, void* d_ws, size_t ws_size,
                              hipStream_t stream) {
  const float* x_in = (const float*)d_in[0];
  const int* edge_index = (const int*)d_in[1];
  const int* batch = (const int*)d_in[2];
  const float* eps = (const float*)d_in[3];
  const float* W1 = (const float*)d_in[4];
  const float* b1 = (const float*)d_in[5];
  const float* W2 = (const float*)d_in[6];
  const float* b2 = (const float*)d_in[7];
  const float* Wc1 = (const float*)d_in[8];
  const float* bc1 = (const float*)d_in[9];
  const float* Wc2 = (const float*)d_in[10];
  const float* bc2 = (const float*)d_in[11];
  float* out = (float*)d_out;

  const int N = N_NODES, E = N_EDGES;
  const int* src = edge_index;
  const int* dst = edge_index + E;

  // workspace layout
  float* xa = (float*)d_ws;                    // N*128 floats
  float* xb = xa + (size_t)N * 128;            // N*128 floats
  int* deg = (int*)(xb + (size_t)N * 128);     // N
  int* rs = deg + N;                           // N+1
  int* cur = rs + (N + 1);                     // N
  int* csr = cur + N;                          // E
  float* pool = (float*)(csr + E);             // 64*128
  int* gcnt = (int*)(pool + NUM_GRAPHS * 128); // 64
  int* psum = gcnt + NUM_GRAPHS;               // SCAN_BLOCKS
  int* poff = psum + SCAN_BLOCKS;              // SCAN_BLOCKS

  hipMemsetAsync(deg, 0, N * sizeof(int), stream);

  // CSR build
  count_deg_kernel<<<(E + 255) / 256, 256, 0, stream>>>(dst, deg, E);
  block_sum_kernel<<<SCAN_BLOCKS, 256, 0, stream>>>(deg, psum, N);
  scan_partials_kernel<<<1, 512, 0, stream>>>(psum, poff, SCAN_BLOCKS);
  write_rs_kernel<<<SCAN_BLOCKS, 256, 0, stream>>>(deg, poff, rs, cur, N);
  fill_csr_kernel<<<(E + 255) / 256, 256, 0, stream>>>(src, dst, cur, csr, E);

  // layers (ping-pong; layer 0 reads the input buffer directly)
  for (int i = 0; i < NUM_LAYERS; ++i) {
    const float* xi = (i == 0) ? x_in : ((i % 2 == 0) ? xb : xa);
    float* xo = (i % 2 == 0) ? xa : xb;
    layer_kernel<<<(N + 63) / 64, 256, 0, stream>>>(xi, xo, rs, csr, eps, i,
                                                    W1 + (size_t)i * 128 * 128, b1 + (size_t)i * 128,
                                                    W2 + (size_t)i * 128 * 128, b2 + (size_t)i * 128,
                                                    N, i > 0 ? 1 : 0);
  }
  const float* xfin = (NUM_LAYERS % 2 == 0) ? xb : xa;

  // pooling + classifier
  hipMemsetAsync(pool, 0, NUM_GRAPHS * 128 * sizeof(float), stream);
  hipMemsetAsync(gcnt, 0, NUM_GRAPHS * sizeof(int), stream);
  pool_kernel<<<(N + 511) / 512, 128, 0, stream>>>(xfin, batch, pool, gcnt, N);
  classifier_kernel<<<NUM_GRAPHS, 128, 0, stream>>>(pool, gcnt, Wc1, bc1, Wc2, bc2, out);
}